// Round 2
// baseline (570.926 us; speedup 1.0000x reference)
//
#include <hip/hip_runtime.h>

// Problem constants (fixed by setup_inputs)
#define CIN   16
#define COUT  32
#define BATCH 2
#define DSP   32
#define HSP   128
#define WSP   128
// Tiling: tile = 4 (z) x 16 (y) x 16 (x) = 1024 voxels; 8x8x8 tiles per batch
#define NTILES      1024            // BATCH * 512
#define BIN_CAP     256
#define LCAP        512             // per-tile halo list capacity
#define COG         8               // c_out per conv block (4 groups)

// ---------------- dedup: last-write-wins voxel -> point map ----------------
__global__ void k_dedup(const int* __restrict__ coords, int* __restrict__ map, int n) {
    int p = blockIdx.x * 256 + threadIdx.x;
    if (p >= n) return;
    int b = coords[p*4+0], z = coords[p*4+1], y = coords[p*4+2], x = coords[p*4+3];
    int vox = ((b*DSP + z)*HSP + y)*WSP + x;
    atomicMax(&map[vox], p);
}

// ---------------- bin winning points by spatial tile ----------------
__global__ void k_bin(const int* __restrict__ coords, const int* __restrict__ map,
                      int* __restrict__ binCnt, int* __restrict__ bins, int n) {
    int p = blockIdx.x * 256 + threadIdx.x;
    if (p >= n) return;
    int b = coords[p*4+0], z = coords[p*4+1], y = coords[p*4+2], x = coords[p*4+3];
    int vox = ((b*DSP + z)*HSP + y)*WSP + x;
    if (map[vox] != p) return;                       // only the winner scatters
    int tile = ((b*8 + (z>>2))*8 + (y>>4))*8 + (x>>4);
    int slot = atomicAdd(&binCnt[tile], 1);
    if (slot < BIN_CAP) bins[tile*BIN_CAP + slot] = p;
}

// ---------------- repack weights: dst[g][kidx][ci][co8] (group-contiguous) ----
// kernel[co][ci][kd][kh][kw] = weight_flat[co*432 + ci*27 + kidx]  (pure reshape)
__global__ void k_repack(const float* __restrict__ w, float* __restrict__ wr) {
    int i = blockIdx.x * 256 + threadIdx.x;          // 4*27*16*8 = 13824
    if (i >= 27*CIN*COUT) return;
    int co = i & 7, ci = (i>>3) & 15;
    int kg = i >> 7;                                  // g*27 + kidx
    int kidx = kg % 27, g = kg / 27;
    wr[i] = w[((g*COG + co)*CIN + ci)*27 + kidx];
}

// ---------------- per-tile halo gather (ONCE per tile, shared by 4 groups) ----
__global__ void k_gather(const int* __restrict__ coords,
                         const int* __restrict__ binCnt, const int* __restrict__ bins,
                         int* __restrict__ tileCnt, int2* __restrict__ tileLst) {
    int tile = blockIdx.x;
    int txi = tile & 7, tyi = (tile>>3) & 7, tzi = (tile>>6) & 7, b = tile >> 9;
    int z0 = tzi << 2, y0 = tyi << 4, x0 = txi << 4;
    __shared__ int lcnt;
    if (threadIdx.x == 0) lcnt = 0;
    __syncthreads();

    for (int dz = -1; dz <= 1; ++dz)
    for (int dy = -1; dy <= 1; ++dy)
    for (int dx = -1; dx <= 1; ++dx) {
        int nz = tzi + dz, ny = tyi + dy, nx = txi + dx;
        if ((unsigned)nz > 7u || (unsigned)ny > 7u || (unsigned)nx > 7u) continue;
        int nt  = ((b*8 + nz)*8 + ny)*8 + nx;
        int cnt = binCnt[nt]; if (cnt > BIN_CAP) cnt = BIN_CAP;
        for (int i = threadIdx.x; i < cnt; i += 256) {
            int p  = bins[nt*BIN_CAP + i];
            int pz = coords[p*4+1], py = coords[p*4+2], px = coords[p*4+3];
            int lz = pz - z0 + 1, ly = py - y0 + 1, lx = px - x0 + 1;
            bool pass = ((unsigned)lz < 6u) && ((unsigned)ly < 18u) && ((unsigned)lx < 18u);
            unsigned long long mb = __ballot(pass);
            if (mb) {                                  // wave-uniform
                int lane   = threadIdx.x & 63;
                int tot    = __popcll(mb);
                int leader = __ffsll((unsigned long long)mb) - 1;
                int bq = 0;
                if (lane == leader) bq = atomicAdd(&lcnt, tot);
                bq = __shfl(bq, leader);
                if (pass) {
                    int s = bq + __popcll(mb & ((1ull << lane) - 1ull));
                    if (s < LCAP)
                        tileLst[tile*LCAP + s] = make_int2(p, (lz<<10) | (ly<<5) | lx);
                }
            }
        }
    }
    __syncthreads();
    if (threadIdx.x == 0) tileCnt[tile] = lcnt < LCAP ? lcnt : LCAP;
}

// ---------------- tiled scatter conv ----------------
__global__ __launch_bounds__(256, 3) void k_conv(
    const float* __restrict__ feat, const float* __restrict__ wr,
    const float* __restrict__ bias, const int* __restrict__ tileCnt,
    const int2* __restrict__ tileLst, float* __restrict__ out)
{
    __shared__ float  acc[COG*1024];     // 32 KB
    __shared__ float4 wl4[27*CIN*COG/4]; // 864 float4 = 13.8 KB

    int bid  = blockIdx.x;
    int g    = bid & 3;                  // c_out group
    int tile = bid >> 2;
    int txi = tile & 7, tyi = (tile>>3) & 7, tzi = (tile>>6) & 7, b = tile >> 9;
    int z0 = tzi << 2, y0 = tyi << 4, x0 = txi << 4;

    // zero accumulator (float4 stores) + stage this group's weights into LDS
    {
        float4* a4 = (float4*)acc;
        for (int i = threadIdx.x; i < COG*1024/4; i += 256) a4[i] = make_float4(0,0,0,0);
        const float4* wsrc = (const float4*)(wr + g*(27*CIN*COG));
        for (int j = threadIdx.x; j < 27*CIN*COG/4; j += 256) wl4[j] = wsrc[j];
    }
    __syncthreads();

    int M = tileCnt[tile];

    for (int base = 0; base < M; base += 256) {
        int idx = base + (int)threadIdx.x;
        bool valid = idx < M;
        if (__ballot(valid) == 0ull) continue;         // whole wave idle -> skip
        int2 e = tileLst[tile*LCAP + (valid ? idx : 0)];
        const float4* fp = (const float4*)(feat + (long)e.x * CIN);
        float4 f0 = fp[0], f1 = fp[1], f2 = fp[2], f3 = fp[3];
        float f[CIN] = { f0.x,f0.y,f0.z,f0.w, f1.x,f1.y,f1.z,f1.w,
                         f2.x,f2.y,f2.z,f2.w, f3.x,f3.y,f3.z,f3.w };
        int lz = e.y >> 10, ly = (e.y >> 5) & 31, lx = e.y & 31;

        #pragma unroll 1
        for (int kd = 0; kd < 3; ++kd)
        #pragma unroll 1
        for (int kh = 0; kh < 3; ++kh)
        #pragma unroll
        for (int kw = 0; kw < 3; ++kw) {
            int tz = lz - kd, ty = ly - kh, tx = lx - kw;   // target local voxel
            bool in = valid && ((unsigned)tz < 4u) && ((unsigned)ty < 16u)
                            && ((unsigned)tx < 16u);
            int kidx = (kd*3 + kh)*3 + kw;
            const float4* wk = &wl4[kidx * (CIN*COG/4)];    // wave-uniform LDS addr
            float c[COG] = {0,0,0,0,0,0,0,0};
            #pragma unroll
            for (int ci = 0; ci < CIN; ++ci) {
                float fv = f[ci];
                float4 wa = wk[ci*2], wb = wk[ci*2+1];
                c[0] += wa.x*fv; c[1] += wa.y*fv; c[2] += wa.z*fv; c[3] += wa.w*fv;
                c[4] += wb.x*fv; c[5] += wb.y*fv; c[6] += wb.z*fv; c[7] += wb.w*fv;
            }
            if (in) {
                int lv = (tz << 8) + (ty << 4) + tx;
                #pragma unroll
                for (int co = 0; co < COG; ++co)
                    atomicAdd(&acc[co*1024 + lv], c[co]);
            }
        }
    }
    __syncthreads();

    // writeback: out = relu(acc + bias), float4 stores, written exactly once
    int cobase = g * COG;
    for (int i4 = (int)threadIdx.x; i4 < (COG*1024)/4; i4 += 256) {
        int i  = i4 * 4;
        int co = i >> 10;
        int lv = i & 1023;
        float4 v = *reinterpret_cast<const float4*>(&acc[co*1024 + lv]);
        float bv = bias[cobase + co];
        v.x = fmaxf(v.x + bv, 0.f); v.y = fmaxf(v.y + bv, 0.f);
        v.z = fmaxf(v.z + bv, 0.f); v.w = fmaxf(v.w + bv, 0.f);
        int tz = lv >> 8, ty = (lv >> 4) & 15, tx = lv & 15;
        long o = ((((long)b*COUT + cobase + co)*DSP + (z0 + tz))*HSP + (y0 + ty))*WSP
                 + (x0 + tx);
        *reinterpret_cast<float4*>(&out[o]) = v;
    }
}

extern "C" void kernel_launch(void* const* d_in, const int* in_sizes, int n_in,
                              void* d_out, int out_size, void* d_ws, size_t ws_size,
                              hipStream_t stream) {
    const float* feat   = (const float*)d_in[0];
    const int*   coords = (const int*)d_in[1];
    const float* weight = (const float*)d_in[2];
    const float* bias   = (const float*)d_in[3];
    float* out = (float*)d_out;
    int n = in_sizes[0] / CIN;                       // number of points

    // workspace layout (all segments 16B-aligned)
    int*   map     = (int*)d_ws;                     // 1,048,576 ints (4 MB)
    int*   binCnt  = map + BATCH*DSP*HSP*WSP;        // 1024 ints
    int*   bins    = binCnt + NTILES;                // 1024*256 ints (1 MB)
    float* wr      = (float*)(bins + NTILES*BIN_CAP);// 13824 floats (55 KB)
    int*   tileCnt = (int*)(wr + 27*CIN*COUT);       // 1024 ints
    int2*  tileLst = (int2*)(tileCnt + NTILES);      // 1024*512 int2 (4 MB)

    hipMemsetAsync(map, 0xFF, (size_t)BATCH*DSP*HSP*WSP*sizeof(int), stream); // -1
    hipMemsetAsync(binCnt, 0, NTILES*sizeof(int), stream);

    int nb = (n + 255) / 256;
    k_dedup <<<nb, 256, 0, stream>>>(coords, map, n);
    k_bin   <<<nb, 256, 0, stream>>>(coords, map, binCnt, bins, n);
    k_repack<<<(27*CIN*COUT + 255)/256, 256, 0, stream>>>(weight, wr);
    k_gather<<<NTILES, 256, 0, stream>>>(coords, binCnt, bins, tileCnt, tileLst);
    k_conv  <<<NTILES*4, 256, 0, stream>>>(feat, wr, bias, tileCnt, tileLst, out);
}

// Round 3
// 132.876 us; speedup vs baseline: 4.2967x; 4.2967x over previous
//
#include <hip/hip_runtime.h>

// Problem constants
#define CIN   16
#define COUT  32
#define BATCH 2
#define DSP   32
#define HSP   128
#define WSP   128

// conv tile: 2(z) x 16(y) x 16(x); halo patch: 4 x 18 x 18
#define TZ 2
#define TY 16
#define TX 16
#define NTZ 16              // DSP/TZ
#define NTY 8               // HSP/TY
#define NTX 8               // WSP/TX
#define NTILES (BATCH*NTZ*NTY*NTX)   // 2048
#define PZ 4
#define PY 18
#define PX 18
#define PVOX (PZ*PY*PX)     // 1296
#define VSTRIDE 24          // bf16 units per patch voxel: 16 payload + 8 pad (48B, bank-spread)
#define BIN_CAP 128
#define NPAIR 14            // 27 taps -> 14 pairs (last padded with zero weights)

typedef __bf16 bf16x8 __attribute__((ext_vector_type(8)));
typedef float  f32x4  __attribute__((ext_vector_type(4)));

// ---------------- dedup: last-write-wins voxel -> point map ----------------
__global__ void k_dedup(const int4* __restrict__ coords, int* __restrict__ map, int n) {
    int p = blockIdx.x * 256 + threadIdx.x;
    if (p >= n) return;
    int4 c = coords[p];
    int vox = ((c.x*DSP + c.y)*HSP + c.z)*WSP + c.w;
    atomicMax(&map[vox], p);
}

// ---------------- bin winning points by conv tile ----------------
__global__ void k_bin(const int4* __restrict__ coords, const int* __restrict__ map,
                      int* __restrict__ binCnt, int* __restrict__ bins, int n) {
    int p = blockIdx.x * 256 + threadIdx.x;
    if (p >= n) return;
    int4 c = coords[p];
    int vox = ((c.x*DSP + c.y)*HSP + c.z)*WSP + c.w;
    if (map[vox] != p) return;                       // only last-writer survives
    int tile = ((c.x*NTZ + (c.y>>1))*NTY + (c.z>>4))*NTX + (c.w>>4);
    int slot = atomicAdd(&binCnt[tile], 1);
    if (slot < BIN_CAP) bins[tile*BIN_CAP + slot] = p;
}

// ------- repack weights into exact MFMA B-fragment lane layout (bf16) -------
// wpack flat idx = ((pair*2 + half)*64 + lane)*8 + j
// B[k=( lane>>4)*8+j][col=lane&15]:  tap = 2*pair + ((lane>>4)>>1), ci = ((lane>>4)&1)*8 + j,
// cout = half*16 + (lane&15).  W(co,ci,tap) = w_flat[(co*CIN+ci)*27 + tap]; tap 27 -> 0.
__global__ void k_repack(const float* __restrict__ w, __bf16* __restrict__ wpack) {
    int i = blockIdx.x * 256 + threadIdx.x;          // 14*2*64*8 = 14336
    if (i >= NPAIR*2*64*8) return;
    int j = i & 7, l = (i>>3) & 63, h = (i>>9) & 1, p = i >> 10;
    int tap = 2*p + ((l>>4)>>1);
    int co  = h*16 + (l & 15);
    int ci  = ((l>>4)&1)*8 + j;
    float v = (tap < 27) ? w[(co*CIN + ci)*27 + tap] : 0.0f;
    wpack[i] = (__bf16)v;
}

// ---------------- dense-tile implicit-GEMM conv (MFMA) ----------------
__global__ __launch_bounds__(256, 2) void k_conv(
    const float* __restrict__ feat, const int4* __restrict__ coords,
    const __bf16* __restrict__ wpack, const float* __restrict__ bias,
    const int* __restrict__ binCnt, const int* __restrict__ bins,
    float* __restrict__ out)
{
    __shared__ __align__(16) ushort patch[PVOX*VSTRIDE];  // 62208 B
    __shared__ int ldsNt[27], ldsCnt[27];

    int tile = blockIdx.x;
    int txi = tile & 7; int t1 = tile >> 3;
    int tyi = t1 & 7;   int t2 = t1 >> 3;
    int tzi = t2 & 15;  int b  = t2 >> 4;
    int z0 = tzi*TZ, y0 = tyi*TY, x0 = txi*TX;

    int tid  = threadIdx.x;
    int lane = tid & 63, wave = tid >> 6;

    // issue neighbor-bin count loads early (one latency for all 27)
    if (tid < 27) {
        int dz = tid/9 - 1, dy = (tid/3)%3 - 1, dx = tid%3 - 1;
        int nz = tzi+dz, ny = tyi+dy, nx = txi+dx;
        bool ok = (unsigned)nz < NTZ && (unsigned)ny < NTY && (unsigned)nx < NTX;
        int nt = ((b*NTZ + nz)*NTY + ny)*NTX + nx;
        ldsNt[tid]  = ok ? nt : 0;
        int c = ok ? binCnt[nt] : 0;
        ldsCnt[tid] = c > BIN_CAP ? BIN_CAP : c;
    }

    // zero patch (3888 x 16B)
    uint4* p4 = (uint4*)patch;
    for (int i = tid; i < PVOX*VSTRIDE/8; i += 256) p4[i] = make_uint4(0,0,0,0);

    // preload all weight fragments into registers (28 coalesced dwordx4)
    bf16x8 wf[NPAIR][2];
    #pragma unroll
    for (int p = 0; p < NPAIR; ++p)
        #pragma unroll
        for (int h = 0; h < 2; ++h)
            wf[p][h] = *(const bf16x8*)(wpack + ((size_t)((p*2 + h)*64 + lane))*8);

    int lx16  = lane & 15;
    int lhalf = (lane >> 4) & 1;
    int ltp   = (lane >> 4) >> 1;

    // per-lane patch offsets per tap-pair (bf16 units)
    int myoff[NPAIR];
    #pragma unroll
    for (int p = 0; p < NPAIR; ++p) {
        int tap = 2*p + ltp; if (tap > 26) tap = 26;   // A reads finite; B is zero there
        int kd = tap/9, kh = (tap/3)%3, kw = tap%3;
        myoff[p] = ((kd*PY + kh)*PX + kw)*VSTRIDE;
    }

    float bv0 = bias[lx16], bv1 = bias[16 + lx16];

    __syncthreads();

    // scatter candidate points from the 27 neighbor bins into the dense patch
    #pragma unroll 1
    for (int k = 0; k < 27; ++k) {
        int cnt = ldsCnt[k];
        if (cnt == 0) continue;
        int nt = ldsNt[k];
        for (int i = tid; i < cnt; i += 256) {
            int p = bins[nt*BIN_CAP + i];
            int4 c = coords[p];
            int lz = c.y - z0 + 1, ly = c.z - y0 + 1, lx = c.w - x0 + 1;
            if ((unsigned)lz < PZ && (unsigned)ly < PY && (unsigned)lx < PX) {
                const float4* fp = (const float4*)(feat + (size_t)p*CIN);
                float4 f0 = fp[0], f1 = fp[1], f2 = fp[2], f3 = fp[3];
                bf16x8 lo = { (__bf16)f0.x,(__bf16)f0.y,(__bf16)f0.z,(__bf16)f0.w,
                              (__bf16)f1.x,(__bf16)f1.y,(__bf16)f1.z,(__bf16)f1.w };
                bf16x8 hi = { (__bf16)f2.x,(__bf16)f2.y,(__bf16)f2.z,(__bf16)f2.w,
                              (__bf16)f3.x,(__bf16)f3.y,(__bf16)f3.z,(__bf16)f3.w };
                int a = ((lz*PY + ly)*PX + lx)*VSTRIDE;  // bf16 units, 16B aligned
                *(bf16x8*)(patch + a)     = lo;
                *(bf16x8*)(patch + a + 8) = hi;
            }
        }
    }
    __syncthreads();

    // compute: 32 groups (z in [0,2), y in [0,16)), 8 per wave
    #pragma unroll 1
    for (int gi = 0; gi < 8; ++gi) {
        int g = wave*8 + gi;
        int z = g >> 4, y = g & 15;
        int laneBase = ((z*PY + y)*PX + lx16)*VSTRIDE + lhalf*8;
        f32x4 acc0 = {0.f,0.f,0.f,0.f}, acc1 = {0.f,0.f,0.f,0.f};
        #pragma unroll
        for (int p = 0; p < NPAIR; ++p) {
            bf16x8 a = *(const bf16x8*)(patch + laneBase + myoff[p]);
            acc0 = __builtin_amdgcn_mfma_f32_16x16x32_bf16(a, wf[p][0], acc0, 0, 0, 0);
            acc1 = __builtin_amdgcn_mfma_f32_16x16x32_bf16(a, wf[p][1], acc1, 0, 0, 0);
        }
        // writeback: D col = lane&15 = cout-in-half, row = (lane>>4)*4+reg = x
        int gz = z0 + z, gy = y0 + y, gx = x0 + ((lane >> 4) << 2);
        float4 o0, o1;
        o0.x = fmaxf(acc0[0]+bv0, 0.f); o0.y = fmaxf(acc0[1]+bv0, 0.f);
        o0.z = fmaxf(acc0[2]+bv0, 0.f); o0.w = fmaxf(acc0[3]+bv0, 0.f);
        o1.x = fmaxf(acc1[0]+bv1, 0.f); o1.y = fmaxf(acc1[1]+bv1, 0.f);
        o1.z = fmaxf(acc1[2]+bv1, 0.f); o1.w = fmaxf(acc1[3]+bv1, 0.f);
        size_t base0 = ((((size_t)b*COUT + lx16)*DSP + gz)*HSP + gy)*WSP + gx;
        size_t base1 = base0 + (size_t)16*DSP*HSP*WSP;
        *(float4*)(out + base0) = o0;
        *(float4*)(out + base1) = o1;
    }
}

extern "C" void kernel_launch(void* const* d_in, const int* in_sizes, int n_in,
                              void* d_out, int out_size, void* d_ws, size_t ws_size,
                              hipStream_t stream) {
    const float* feat   = (const float*)d_in[0];
    const int4*  coords = (const int4*)d_in[1];
    const float* weight = (const float*)d_in[2];
    const float* bias   = (const float*)d_in[3];
    float* out = (float*)d_out;
    int n = in_sizes[0] / CIN;

    // workspace: map 4MB | binCnt 8KB | bins 1MB | wpack 28KB  (~5MB total)
    int*    map    = (int*)d_ws;
    int*    binCnt = map + BATCH*DSP*HSP*WSP;
    int*    bins   = binCnt + NTILES;
    __bf16* wpack  = (__bf16*)(bins + NTILES*BIN_CAP);

    hipMemsetAsync(map, 0xFF, (size_t)BATCH*DSP*HSP*WSP*sizeof(int), stream);
    hipMemsetAsync(binCnt, 0, NTILES*sizeof(int), stream);

    int nb = (n + 255) / 256;
    k_dedup <<<nb, 256, 0, stream>>>(coords, map, n);
    k_bin   <<<nb, 256, 0, stream>>>(coords, map, binCnt, bins, n);
    k_repack<<<(NPAIR*2*64*8 + 255)/256, 256, 0, stream>>>(weight, wpack);
    k_conv  <<<NTILES, 256, 0, stream>>>(feat, coords, wpack, bias, binCnt, bins, out);
}

// Round 4
// 79.412 us; speedup vs baseline: 7.1894x; 1.6732x over previous
//
#include <hip/hip_runtime.h>

// Problem constants
#define CIN   16
#define COUT  32
#define BATCH 2
#define DSP   32
#define HSP   128
#define WSP   128

// conv tile: 4(z) x 8(y) x 16(x); halo patch 6 x 10 x 18
#define TZ 4
#define TY 8
#define TX 16
#define NTZ 8               // DSP/TZ
#define NTY 16              // HSP/TY
#define NTX 8               // WSP/TX
#define NTILES (BATCH*NTZ*NTY*NTX)   // 2048
#define PZ 6
#define PY 10
#define PX 18
#define PVOX (PZ*PY*PX)     // 1080
#define HALFU (PVOX*8)      // ushort units per ci-half (8640)
#define BIN_CAP 128
#define NPAIR 14            // 27 taps -> 14 K=32 pairs (last padded with zero weights)

typedef __bf16 bf16x8 __attribute__((ext_vector_type(8)));
typedef float  f32x4  __attribute__((ext_vector_type(4)));

// ------------- fused: dedup (last-write-wins) + weight repack -------------
// wpack flat idx = ((pair*2 + half)*64 + lane)*8 + j
// tap = 2*pair + ((lane>>4)>>1), ci = ((lane>>4)&1)*8 + j, cout = half*16 + (lane&15)
__global__ void k_prep(const int4* __restrict__ coords, int n, int nbDedup,
                       int* __restrict__ map,
                       const float* __restrict__ w, __bf16* __restrict__ wpack) {
    if ((int)blockIdx.x < nbDedup) {
        int p = blockIdx.x * 256 + threadIdx.x;
        if (p >= n) return;
        int4 c = coords[p];
        int vox = ((c.x*DSP + c.y)*HSP + c.z)*WSP + c.w;
        atomicMax(&map[vox], p);
    } else {
        int i = (blockIdx.x - nbDedup) * 256 + threadIdx.x;  // 14336 total
        if (i >= NPAIR*2*64*8) return;
        int j = i & 7, l = (i>>3) & 63, h = (i>>9) & 1, p = i >> 10;
        int tap = 2*p + ((l>>4)>>1);
        int co  = h*16 + (l & 15);
        int ci  = ((l>>4)&1)*8 + j;
        float v = (tap < 27) ? w[(co*CIN + ci)*27 + tap] : 0.0f;
        wpack[i] = (__bf16)v;
    }
}

// ---------------- bin winning points by conv tile ----------------
__global__ void k_bin(const int4* __restrict__ coords, const int* __restrict__ map,
                      int* __restrict__ binCnt, int* __restrict__ bins, int n) {
    int p = blockIdx.x * 256 + threadIdx.x;
    if (p >= n) return;
    int4 c = coords[p];
    int vox = ((c.x*DSP + c.y)*HSP + c.z)*WSP + c.w;
    if (map[vox] != p) return;                       // only last-writer survives
    int tile = ((c.x*NTZ + (c.y>>2))*NTY + (c.z>>3))*NTX + (c.w>>4);
    int slot = atomicAdd(&binCnt[tile], 1);
    if (slot < BIN_CAP) bins[tile*BIN_CAP + slot] = p;
}

// ---------------- dense-tile implicit-GEMM conv (MFMA) ----------------
__global__ __launch_bounds__(256, 3) void k_conv(
    const float* __restrict__ feat, const int4* __restrict__ coords,
    const __bf16* __restrict__ wpack, const float* __restrict__ bias,
    const int* __restrict__ binCnt, const int* __restrict__ bins,
    float* __restrict__ out)
{
    __shared__ __align__(16) ushort patch[2*HALFU];   // 34560 B (lo | hi ci-halves)
    __shared__ int ldsNt[27], ldsCnt[27], ldsPre[27];

    int tile = blockIdx.x;
    int txi = tile & 7;
    int tyi = (tile >> 3) & 15;
    int tzi = (tile >> 7) & 7;
    int b   = tile >> 10;
    int z0 = tzi*TZ, y0 = tyi*TY, x0 = txi*TX;

    int tid  = threadIdx.x;
    int lane = tid & 63, wave = tid >> 6;

    // issue all 27 neighbor-bin count loads in one latency
    if (tid < 27) {
        int dz = tid/9 - 1, dy = (tid/3)%3 - 1, dx = tid%3 - 1;
        int nz = tzi+dz, ny = tyi+dy, nx = txi+dx;
        bool ok = (unsigned)nz < NTZ && (unsigned)ny < NTY && (unsigned)nx < NTX;
        int nt = ((b*NTZ + nz)*NTY + ny)*NTX + nx;
        ldsNt[tid]  = ok ? nt : 0;
        int c = ok ? binCnt[nt] : 0;
        ldsCnt[tid] = c > BIN_CAP ? BIN_CAP : c;
    }

    // zero patch (2160 x 16B)
    uint4* p4 = (uint4*)patch;
    for (int i = tid; i < 2*HALFU/8; i += 256) p4[i] = make_uint4(0,0,0,0);

    // preload all weight fragments into registers (28 coalesced dwordx4)
    bf16x8 wf[NPAIR][2];
    #pragma unroll
    for (int p = 0; p < NPAIR; ++p)
        #pragma unroll
        for (int h = 0; h < 2; ++h)
            wf[p][h] = *(const bf16x8*)(wpack + ((size_t)((p*2 + h)*64 + lane))*8);

    int lx16  = lane & 15;
    int lhalf = (lane >> 4) & 1;
    int ltp   = (lane >> 4) >> 1;

    // per-lane patch voxel offsets per tap-pair
    int voff[NPAIR];
    #pragma unroll
    for (int p = 0; p < NPAIR; ++p) {
        int tap = 2*p + ltp; if (tap > 26) tap = 26;   // A read in-bounds; B zero there
        int kd = tap/9, kh = (tap/3)%3, kw = tap%3;
        voff[p] = (kd*PY + kh)*PX + kw;
    }

    float bv0 = bias[lx16], bv1 = bias[16 + lx16];

    __syncthreads();

    // exclusive->inclusive prefix over 27 counts (wave 0)
    if (tid < 32) {
        int c = (tid < 27) ? ldsCnt[tid] : 0;
        #pragma unroll
        for (int off = 1; off < 32; off <<= 1) {
            int nvl = __shfl_up(c, off);
            if (tid >= off) c += nvl;
        }
        if (tid < 27) ldsPre[tid] = c;                 // inclusive prefix
    }
    __syncthreads();

    // flattened parallel sweep over all candidates of all 27 bins
    int total = ldsPre[26];
    for (int i = tid; i < total; i += 256) {
        int lo = 0, hi = 26;
        #pragma unroll
        for (int it = 0; it < 5; ++it) {               // ceil(log2 27)
            int mid = (lo + hi) >> 1;
            if (i < ldsPre[mid]) hi = mid; else lo = mid + 1;
        }
        int k = lo;
        int idx = i - (k ? ldsPre[k-1] : 0);
        int p = bins[ldsNt[k]*BIN_CAP + idx];
        int4 c = coords[p];
        int lz = c.y - z0 + 1, ly = c.z - y0 + 1, lx = c.w - x0 + 1;
        if ((unsigned)lz < PZ && (unsigned)ly < PY && (unsigned)lx < PX) {
            const float4* fp = (const float4*)(feat + (size_t)p*CIN);
            float4 f0 = fp[0], f1 = fp[1], f2 = fp[2], f3 = fp[3];
            bf16x8 vlo = { (__bf16)f0.x,(__bf16)f0.y,(__bf16)f0.z,(__bf16)f0.w,
                           (__bf16)f1.x,(__bf16)f1.y,(__bf16)f1.z,(__bf16)f1.w };
            bf16x8 vhi = { (__bf16)f2.x,(__bf16)f2.y,(__bf16)f2.z,(__bf16)f2.w,
                           (__bf16)f3.x,(__bf16)f3.y,(__bf16)f3.z,(__bf16)f3.w };
            int v = (lz*PY + ly)*PX + lx;
            *(bf16x8*)(patch + v*8)         = vlo;
            *(bf16x8*)(patch + HALFU + v*8) = vhi;
        }
    }
    __syncthreads();

    // compute: 32 groups (z in [0,4), y in [0,8)), 8 per wave
    #pragma unroll 1
    for (int gi = 0; gi < 8; ++gi) {
        int g = wave*8 + gi;
        int z = g >> 3, y = g & 7;
        int laneVox = (z*PY + y)*PX + lx16;
        const ushort* pbase = patch + lhalf*HALFU + laneVox*8;
        f32x4 acc0 = {0.f,0.f,0.f,0.f}, acc1 = {0.f,0.f,0.f,0.f};
        #pragma unroll
        for (int p = 0; p < NPAIR; ++p) {
            bf16x8 a = *(const bf16x8*)(pbase + voff[p]*8);
            acc0 = __builtin_amdgcn_mfma_f32_16x16x32_bf16(a, wf[p][0], acc0, 0, 0, 0);
            acc1 = __builtin_amdgcn_mfma_f32_16x16x32_bf16(a, wf[p][1], acc1, 0, 0, 0);
        }
        // writeback: D col = lane&15 = cout-in-half, row = (lane>>4)*4+reg = x
        int gz = z0 + z, gy = y0 + y, gx = x0 + ((lane >> 4) << 2);
        float4 o0, o1;
        o0.x = fmaxf(acc0[0]+bv0, 0.f); o0.y = fmaxf(acc0[1]+bv0, 0.f);
        o0.z = fmaxf(acc0[2]+bv0, 0.f); o0.w = fmaxf(acc0[3]+bv0, 0.f);
        o1.x = fmaxf(acc1[0]+bv1, 0.f); o1.y = fmaxf(acc1[1]+bv1, 0.f);
        o1.z = fmaxf(acc1[2]+bv1, 0.f); o1.w = fmaxf(acc1[3]+bv1, 0.f);
        size_t base0 = ((((size_t)b*COUT + lx16)*DSP + gz)*HSP + gy)*WSP + gx;
        size_t base1 = base0 + (size_t)16*DSP*HSP*WSP;
        *(float4*)(out + base0) = o0;
        *(float4*)(out + base1) = o1;
    }
}

extern "C" void kernel_launch(void* const* d_in, const int* in_sizes, int n_in,
                              void* d_out, int out_size, void* d_ws, size_t ws_size,
                              hipStream_t stream) {
    const float* feat   = (const float*)d_in[0];
    const int4*  coords = (const int4*)d_in[1];
    const float* weight = (const float*)d_in[2];
    const float* bias   = (const float*)d_in[3];
    float* out = (float*)d_out;
    int n = in_sizes[0] / CIN;

    // workspace: map 4MB | binCnt 8KB | bins 1MB | wpack 28KB
    int*    map    = (int*)d_ws;
    int*    binCnt = map + BATCH*DSP*HSP*WSP;
    int*    bins   = binCnt + NTILES;
    __bf16* wpack  = (__bf16*)(bins + NTILES*BIN_CAP);

    hipMemsetAsync(map, 0xFF, (size_t)BATCH*DSP*HSP*WSP*sizeof(int), stream);
    hipMemsetAsync(binCnt, 0, NTILES*sizeof(int), stream);

    int nb = (n + 255) / 256;
    int nbRepack = (NPAIR*2*64*8 + 255) / 256;       // 56
    k_prep<<<nb + nbRepack, 256, 0, stream>>>(coords, n, nb, map, weight, wpack);
    k_bin <<<nb, 256, 0, stream>>>(coords, map, binCnt, bins, n);
    k_conv<<<NTILES, 256, 0, stream>>>(feat, coords, wpack, bias, binCnt, bins, out);
}

// Round 5
// 75.341 us; speedup vs baseline: 7.5779x; 1.0540x over previous
//
#include <hip/hip_runtime.h>

// Problem constants
#define CIN   16
#define COUT  32
#define BATCH 2
#define DSP   32
#define HSP   128
#define WSP   128

// conv tile: 4(z) x 8(y) x 16(x); halo patch 6 x 10 x 18
#define TZ 4
#define TY 8
#define TX 16
#define NTZ 8               // DSP/TZ
#define NTY 16              // HSP/TY
#define NTX 8               // WSP/TX
#define NTILES (BATCH*NTZ*NTY*NTX)   // 2048
#define PZ 6
#define PY 10
#define PX 18
#define PVOX (PZ*PY*PX)     // 1080
#define HALFU (PVOX*8)      // ushort units per ci-half (8640)
#define BIN_CAP 128
#define NPAIR 14            // 27 taps -> 14 K=32 pairs (last padded with zero weights)
#define NWREP ((NPAIR*2*64*8 + 255)/256)   // 56 repack blocks
#define NZB   ((NTILES + 255)/256)         // 8 binCnt-zero blocks

typedef __bf16 bf16x8 __attribute__((ext_vector_type(8)));
typedef float  f32x4  __attribute__((ext_vector_type(4)));

// ---- fused: dedup (last-write-wins) + weight repack + binCnt zero ----
// wpack flat idx = ((pair*2 + half)*64 + lane)*8 + j
// tap = 2*pair + ((lane>>4)>>1), ci = ((lane>>4)&1)*8 + j, cout = half*16 + (lane&15)
__global__ void k_prep(const int4* __restrict__ coords, int n, int nbDedup,
                       int* __restrict__ map,
                       const float* __restrict__ w, __bf16* __restrict__ wpack,
                       int* __restrict__ binCnt) {
    int bb = blockIdx.x;
    if (bb < nbDedup) {
        int p = bb * 256 + threadIdx.x;
        if (p >= n) return;
        int4 c = coords[p];
        int vox = ((c.x*DSP + c.y)*HSP + c.z)*WSP + c.w;
        atomicMax(&map[vox], p);
    } else if (bb < nbDedup + NWREP) {
        int i = (bb - nbDedup) * 256 + threadIdx.x;   // 14336 total
        if (i >= NPAIR*2*64*8) return;
        int j = i & 7, l = (i>>3) & 63, h = (i>>9) & 1, p = i >> 10;
        int tap = 2*p + ((l>>4)>>1);
        int co  = h*16 + (l & 15);
        int ci  = ((l>>4)&1)*8 + j;
        float v = (tap < 27) ? w[(co*CIN + ci)*27 + tap] : 0.0f;
        wpack[i] = (__bf16)v;
    } else {
        int i = (bb - nbDedup - NWREP) * 256 + threadIdx.x;
        if (i < NTILES) binCnt[i] = 0;
    }
}

// ---- bin winners by conv tile; store point idx + packed coords ----
__global__ void k_bin(const int4* __restrict__ coords, const int* __restrict__ map,
                      int* __restrict__ binCnt, int2* __restrict__ bins, int n) {
    int p = blockIdx.x * 256 + threadIdx.x;
    if (p >= n) return;
    int4 c = coords[p];
    int vox = ((c.x*DSP + c.y)*HSP + c.z)*WSP + c.w;
    if (map[vox] != p) return;                       // only last-writer survives
    int tile = ((c.x*NTZ + (c.y>>2))*NTY + (c.z>>3))*NTX + (c.w>>4);
    int slot = atomicAdd(&binCnt[tile], 1);
    if (slot < BIN_CAP)
        bins[tile*BIN_CAP + slot] = make_int2(p, (c.y<<14) | (c.z<<7) | c.w);
}

// ---------------- dense-tile implicit-GEMM conv (MFMA) ----------------
__global__ __launch_bounds__(256, 4) void k_conv(
    const float* __restrict__ feat, const __bf16* __restrict__ wpack,
    const float* __restrict__ bias, const int* __restrict__ binCnt,
    const int2* __restrict__ bins, float* __restrict__ out)
{
    __shared__ __align__(16) ushort patch[2*HALFU];   // 34560 B (lo | hi ci-halves)
    __shared__ int ldsNt[27], ldsCnt[27], ldsPre[27];

    int tile = blockIdx.x;
    int txi = tile & 7;
    int tyi = (tile >> 3) & 15;
    int tzi = (tile >> 7) & 7;
    int b   = tile >> 10;
    int z0 = tzi*TZ, y0 = tyi*TY, x0 = txi*TX;

    int tid  = threadIdx.x;
    int lane = tid & 63, wave = tid >> 6;

    // issue all 27 neighbor-bin count loads in one latency
    if (tid < 27) {
        int dz = tid/9 - 1, dy = (tid/3)%3 - 1, dx = tid%3 - 1;
        int nz = tzi+dz, ny = tyi+dy, nx = txi+dx;
        bool ok = (unsigned)nz < NTZ && (unsigned)ny < NTY && (unsigned)nx < NTX;
        int nt = ((b*NTZ + nz)*NTY + ny)*NTX + nx;
        ldsNt[tid]  = ok ? nt : 0;
        int c = ok ? binCnt[nt] : 0;
        ldsCnt[tid] = c > BIN_CAP ? BIN_CAP : c;
    }

    // zero patch (2160 x 16B)
    uint4* p4 = (uint4*)patch;
    for (int i = tid; i < 2*HALFU/8; i += 256) p4[i] = make_uint4(0,0,0,0);

    int lx16  = lane & 15;
    int lhalf = (lane >> 4) & 1;
    int ltp   = (lane >> 4) >> 1;

    // per-lane patch voxel offsets per tap-pair
    int voff[NPAIR];
    #pragma unroll
    for (int p = 0; p < NPAIR; ++p) {
        int tap = 2*p + ltp; if (tap > 26) tap = 26;   // A read in-bounds; B zero there
        int kd = tap/9, kh = (tap/3)%3, kw = tap%3;
        voff[p] = (kd*PY + kh)*PX + kw;
    }

    float bv0 = bias[lx16], bv1 = bias[16 + lx16];

    __syncthreads();

    // inclusive prefix over 27 counts (wave 0)
    if (tid < 32) {
        int c = (tid < 27) ? ldsCnt[tid] : 0;
        #pragma unroll
        for (int off = 1; off < 32; off <<= 1) {
            int nvl = __shfl_up(c, off);
            if (tid >= off) c += nvl;
        }
        if (tid < 27) ldsPre[tid] = c;
    }
    __syncthreads();

    // flattened parallel sweep over all candidates of all 27 bins
    int total = ldsPre[26];
    #pragma unroll 2
    for (int i = tid; i < total; i += 256) {
        int lo = 0, hi = 26;
        #pragma unroll
        for (int it = 0; it < 5; ++it) {               // ceil(log2 27)
            int mid = (lo + hi) >> 1;
            if (i < ldsPre[mid]) hi = mid; else lo = mid + 1;
        }
        int k = lo;
        int idx = i - (k ? ldsPre[k-1] : 0);
        int2 e = bins[ldsNt[k]*BIN_CAP + idx];
        int pz = e.y >> 14, py = (e.y >> 7) & 127, px = e.y & 127;
        int lz = pz - z0 + 1, ly = py - y0 + 1, lx = px - x0 + 1;
        if ((unsigned)lz < PZ && (unsigned)ly < PY && (unsigned)lx < PX) {
            const float4* fp = (const float4*)(feat + (size_t)e.x*CIN);
            float4 f0 = fp[0], f1 = fp[1], f2 = fp[2], f3 = fp[3];
            bf16x8 vlo = { (__bf16)f0.x,(__bf16)f0.y,(__bf16)f0.z,(__bf16)f0.w,
                           (__bf16)f1.x,(__bf16)f1.y,(__bf16)f1.z,(__bf16)f1.w };
            bf16x8 vhi = { (__bf16)f2.x,(__bf16)f2.y,(__bf16)f2.z,(__bf16)f2.w,
                           (__bf16)f3.x,(__bf16)f3.y,(__bf16)f3.z,(__bf16)f3.w };
            int v = (lz*PY + ly)*PX + lx;
            *(bf16x8*)(patch + v*8)         = vlo;
            *(bf16x8*)(patch + HALFU + v*8) = vhi;
        }
    }
    __syncthreads();

    // compute: pair-outer / group-inner, 1-deep weight prefetch.
    // wave = z (4 z-layers), gi = y (8 rows); acc[gi][half], all statically indexed.
    const ushort* pb = patch + lhalf*HALFU + ((wave*PY)*PX + lx16)*8;
    f32x4 acc[8][2];
    #pragma unroll
    for (int gi = 0; gi < 8; ++gi) {
        acc[gi][0] = (f32x4){0.f,0.f,0.f,0.f};
        acc[gi][1] = (f32x4){0.f,0.f,0.f,0.f};
    }
    bf16x8 w0 = *(const bf16x8*)(wpack + (size_t)(0*64 + lane)*8);
    bf16x8 w1 = *(const bf16x8*)(wpack + (size_t)(1*64 + lane)*8);
    #pragma unroll
    for (int p = 0; p < NPAIR; ++p) {
        int pn = (p + 1 < NPAIR) ? p + 1 : 0;          // last prefetch harmless
        bf16x8 nw0 = *(const bf16x8*)(wpack + (size_t)((pn*2+0)*64 + lane)*8);
        bf16x8 nw1 = *(const bf16x8*)(wpack + (size_t)((pn*2+1)*64 + lane)*8);
        const ushort* pa = pb + voff[p]*8;
        #pragma unroll
        for (int gi = 0; gi < 8; ++gi) {
            bf16x8 a = *(const bf16x8*)(pa + gi*(PX*8));
            acc[gi][0] = __builtin_amdgcn_mfma_f32_16x16x32_bf16(a, w0, acc[gi][0], 0,0,0);
            acc[gi][1] = __builtin_amdgcn_mfma_f32_16x16x32_bf16(a, w1, acc[gi][1], 0,0,0);
        }
        w0 = nw0; w1 = nw1;
    }

    // writeback: D col = lane&15 = cout-in-half, row = (lane>>4)*4+reg = x
    #pragma unroll
    for (int gi = 0; gi < 8; ++gi) {
        int gz = z0 + wave, gy = y0 + gi, gx = x0 + ((lane >> 4) << 2);
        f32x4 o0, o1;
        o0[0] = fmaxf(acc[gi][0][0]+bv0, 0.f); o0[1] = fmaxf(acc[gi][0][1]+bv0, 0.f);
        o0[2] = fmaxf(acc[gi][0][2]+bv0, 0.f); o0[3] = fmaxf(acc[gi][0][3]+bv0, 0.f);
        o1[0] = fmaxf(acc[gi][1][0]+bv1, 0.f); o1[1] = fmaxf(acc[gi][1][1]+bv1, 0.f);
        o1[2] = fmaxf(acc[gi][1][2]+bv1, 0.f); o1[3] = fmaxf(acc[gi][1][3]+bv1, 0.f);
        size_t base0 = ((((size_t)b*COUT + lx16)*DSP + gz)*HSP + gy)*WSP + gx;
        size_t base1 = base0 + (size_t)16*DSP*HSP*WSP;
        __builtin_nontemporal_store(o0, (f32x4*)(out + base0));
        __builtin_nontemporal_store(o1, (f32x4*)(out + base1));
    }
}

extern "C" void kernel_launch(void* const* d_in, const int* in_sizes, int n_in,
                              void* d_out, int out_size, void* d_ws, size_t ws_size,
                              hipStream_t stream) {
    const float* feat   = (const float*)d_in[0];
    const int4*  coords = (const int4*)d_in[1];
    const float* weight = (const float*)d_in[2];
    const float* bias   = (const float*)d_in[3];
    float* out = (float*)d_out;
    int n = in_sizes[0] / CIN;

    // workspace: map 4MB | binCnt 8KB | bins(int2) 2MB | wpack 28KB
    int*    map    = (int*)d_ws;
    int*    binCnt = map + BATCH*DSP*HSP*WSP;
    int2*   bins   = (int2*)(binCnt + NTILES);
    __bf16* wpack  = (__bf16*)(bins + NTILES*BIN_CAP);

    hipMemsetAsync(map, 0xFF, (size_t)BATCH*DSP*HSP*WSP*sizeof(int), stream);

    int nb = (n + 255) / 256;
    k_prep<<<nb + NWREP + NZB, 256, 0, stream>>>(coords, n, nb, map, weight, wpack, binCnt);
    k_bin <<<nb, 256, 0, stream>>>(coords, map, binCnt, bins, n);
    k_conv<<<NTILES, 256, 0, stream>>>(feat, wpack, bias, binCnt, bins, out);
}